// Round 3
// baseline (271.117 us; speedup 1.0000x reference)
//
#include <hip/hip_runtime.h>

#define DIM   1024
#define DST   16
#define NSEQ  8192
#define NB    4

#define MT    64      // rows (n) per tile
#define KC    128     // K-chunk staged per iteration
#define KCP   132     // padded LDS row stride for at (2-way aliasing = free)
#define NTILE 128     // NSEQ / MT

// ---------------------------------------------------------------------------
// Kernel A: T = x_tile @ A with 4rows x 4s register blocking (8 LDS b128
// reads per 64 FMAs vs 5 per 16 before => 2.5x fewer LDS-issue cycles; kA
// was LDS-issue-bound at ~51us). The 4 waves split K into quarters; a final
// LDS reduction folds the 4 partials. xs is unpadded [64][128] with XOR
// quad-swizzle q^=((row>>2)&7) on write AND read: 16-row-stride-4 reads hit
// 8 distinct bank-quads (2-way = free). Then intra-tile scan as before.
// ---------------------------------------------------------------------------
__global__ __launch_bounds__(256) void kA_gemm_scan(
    const float* __restrict__ x, const float* __restrict__ A,
    float* __restrict__ Tloc, float* __restrict__ TS)
{
    __shared__ float xs[MT * KC];         // 32,768 B (swizzled quads)
    __shared__ float at[DST * KCP];       //  8,448 B
    __shared__ float scanbuf[16 * DST];   //  1,024 B

    const int t    = threadIdx.x;
    const int b    = blockIdx.x >> 7;
    const int tile = blockIdx.x & 127;
    const int n0   = tile * MT;

    const int kq4 = t >> 6;          // wave id = k-quarter (0..3)
    const int mg  = (t >> 2) & 15;   // row group (4 rows each)
    const int sp  = t & 3;           // s = sp + 4j, j=0..3

    const float* xrow = x + ((long)(b * NSEQ + n0)) * DIM;

    float acc[4][4];                 // [row r][s-slot j]
    #pragma unroll
    for (int r = 0; r < 4; ++r)
        #pragma unroll
        for (int j = 0; j < 4; ++j) acc[r][j] = 0.f;

    const int kbase = kq4 * 32;      // this wave's k-quarter within the chunk

    for (int kc = 0; kc < DIM; kc += KC) {
        {   // stage x tile, swizzled: quad q -> q ^ ((row>>2)&7)
            const int q  = t & 31;
            const int r0 = t >> 5;
            #pragma unroll
            for (int it = 0; it < 8; ++it) {
                const int m  = it * 8 + r0;
                const float4 v = *(const float4*)(xrow + (long)m * DIM + kc + 4 * q);
                const int qs = q ^ ((m >> 2) & 7);
                *(float4*)&xs[m * KC + 4 * qs] = v;
            }
        }
        {   // stage A^T chunk: at[s][k] from A[k][s]
            #pragma unroll
            for (int it = 0; it < 8; ++it) {
                const int idx = it * 256 + t;
                const int kl  = idx >> 4;
                const int ss  = idx & 15;
                at[ss * KCP + kl] = A[(kc + kl) * DST + ss];
            }
        }
        __syncthreads();

        #pragma unroll
        for (int kq = 0; kq < 8; ++kq) {
            const int kqi = (kbase >> 2) + kq;    // quad index 0..31
            const float4 a0 = *(const float4*)&at[(sp +  0) * KCP + kbase + 4 * kq];
            const float4 a1 = *(const float4*)&at[(sp +  4) * KCP + kbase + 4 * kq];
            const float4 a2 = *(const float4*)&at[(sp +  8) * KCP + kbase + 4 * kq];
            const float4 a3 = *(const float4*)&at[(sp + 12) * KCP + kbase + 4 * kq];
            const int qs = kqi ^ (mg & 7);        // matches write swizzle (row>>2 = mg)
            #pragma unroll
            for (int r = 0; r < 4; ++r) {
                const float4 xv = *(const float4*)&xs[(mg * 4 + r) * KC + 4 * qs];
                acc[r][0] += xv.x * a0.x + xv.y * a0.y + xv.z * a0.z + xv.w * a0.w;
                acc[r][1] += xv.x * a1.x + xv.y * a1.y + xv.z * a1.z + xv.w * a1.w;
                acc[r][2] += xv.x * a2.x + xv.y * a2.y + xv.z * a2.z + xv.w * a2.w;
                acc[r][3] += xv.x * a3.x + xv.y * a3.y + xv.z * a3.z + xv.w * a3.w;
            }
        }
        __syncthreads();
    }

    // ---- reduce the 4 k-quarter partials via LDS (aliases xs, now dead) ---
    float* red = xs;                 // [4][64][17] = 4352 floats < 8192
    #pragma unroll
    for (int r = 0; r < 4; ++r)
        #pragma unroll
        for (int j = 0; j < 4; ++j)
            red[kq4 * (64 * 17) + (mg * 4 + r) * 17 + (sp + 4 * j)] = acc[r][j];
    __syncthreads();

    const int s   = t & 15;          // final ownership: thread (s, mg2)
    const int mg2 = t >> 4;
    float acc0 = 0.f, acc1 = 0.f, acc2 = 0.f, acc3 = 0.f;
    #pragma unroll
    for (int q = 0; q < 4; ++q) {
        const float* rq = red + q * (64 * 17) + (mg2 * 4) * 17 + s;
        acc0 += rq[0 * 17];
        acc1 += rq[1 * 17];
        acc2 += rq[2 * 17];
        acc3 += rq[3 * 17];
    }
    __syncthreads();   // red (=xs) reads done before scanbuf phase reuses nothing, but keep ordering clean

    // ---- intra-tile inclusive scan over the 64 rows of this tile ----------
    const float rsum = acc0 + acc1 + acc2 + acc3;
    scanbuf[mg2 * DST + s] = rsum;
    __syncthreads();
    float excl = 0.f, total = 0.f;
    #pragma unroll
    for (int m = 0; m < 16; ++m) {
        const float v = scanbuf[m * DST + s];
        total += v;
        excl  += (m < mg2) ? v : 0.f;
    }
    if (mg2 == 0) TS[((long)b * NTILE + tile) * DST + s] = total;

    const float c0 = excl + acc0;
    const float c1 = c0 + acc1;
    const float c2 = c1 + acc2;
    const float c3 = c2 + acc3;
    *(float4*)&Tloc[((long)(b * DST + s)) * NSEQ + n0 + mg2 * 4] =
        make_float4(c0, c1, c2, c3);
}

// ---------------------------------------------------------------------------
// Kernel B: per-tile prefix base from TS (L2-hot), then out = (Tloc+base) @ D.
// Store-bound (~134 MB out) -> already near floor; unchanged.
// ---------------------------------------------------------------------------
__global__ __launch_bounds__(256) void kB_scan_out(
    const float* __restrict__ Tloc, const float* __restrict__ TS,
    const float* __restrict__ D, float* __restrict__ out)
{
    __shared__ float sp[MT * 20];
    __shared__ float partial[16 * DST];
    __shared__ float basebuf[DST];

    const int t    = threadIdx.x;
    const int b    = blockIdx.x >> 7;
    const int tile = blockIdx.x & 127;
    const int n0   = tile * MT;
    const int s    = t & 15;
    const int mg   = t >> 4;

    float4 dreg[16];
    #pragma unroll
    for (int ss = 0; ss < 16; ++ss)
        dreg[ss] = *(const float4*)&D[ss * DIM + 4 * t];

    {
        const float* tsb = TS + (long)b * NTILE * DST;
        float p = 0.f;
        for (int j = mg; j < tile; j += 16) p += tsb[j * DST + s];
        partial[mg * DST + s] = p;
    }
    __syncthreads();
    {
        float bsum = 0.f;
        #pragma unroll
        for (int m = 0; m < 16; ++m) bsum += partial[m * DST + s];
        if (mg == 0) basebuf[s] = bsum;
    }
    __syncthreads();

    #pragma unroll
    for (int j = 0; j < 4; ++j) {
        const int idx = j * 256 + t;
        const int ss  = idx >> 6;
        const int nn  = idx & 63;
        sp[nn * 20 + ss] = Tloc[((long)(b * DST + ss)) * NSEQ + n0 + nn] + basebuf[ss];
    }
    __syncthreads();

    float* ob = out + ((long)(b * NSEQ + n0)) * DIM + 4 * t;
    for (int r = 0; r < MT; ++r) {
        const float4 s0 = *(const float4*)&sp[r * 20 + 0];
        const float4 s1 = *(const float4*)&sp[r * 20 + 4];
        const float4 s2 = *(const float4*)&sp[r * 20 + 8];
        const float4 s3 = *(const float4*)&sp[r * 20 + 12];
        const float sv[16] = {s0.x, s0.y, s0.z, s0.w, s1.x, s1.y, s1.z, s1.w,
                              s2.x, s2.y, s2.z, s2.w, s3.x, s3.y, s3.z, s3.w};
        float4 o = make_float4(0.f, 0.f, 0.f, 0.f);
        #pragma unroll
        for (int ss = 0; ss < 16; ++ss) {
            o.x += sv[ss] * dreg[ss].x;
            o.y += sv[ss] * dreg[ss].y;
            o.z += sv[ss] * dreg[ss].z;
            o.w += sv[ss] * dreg[ss].w;
        }
        *(float4*)(ob + (long)r * DIM) = o;
    }
}

// ---------------------------------------------------------------------------
extern "C" void kernel_launch(void* const* d_in, const int* in_sizes, int n_in,
                              void* d_out, int out_size, void* d_ws, size_t ws_size,
                              hipStream_t stream) {
    const float* x = (const float*)d_in[0];   // [4, 8192, 1024]
    const float* A = (const float*)d_in[1];   // [1024, 16]
    const float* D = (const float*)d_in[2];   // [16, 1024]
    float* out  = (float*)d_out;              // [4, 8192, 1024]
    float* Tloc = (float*)d_ws;               // [4, 16, 8192] = 2 MiB
    float* TS   = Tloc + (long)NB * DST * NSEQ;  // [4, 128, 16] = 32 KiB

    kA_gemm_scan<<<dim3(NB * NTILE), dim3(256), 0, stream>>>(x, A, Tloc, TS);
    kB_scan_out <<<dim3(NB * NTILE), dim3(256), 0, stream>>>(Tloc, TS, D, out);
}